// Round 2
// baseline (609.784 us; speedup 1.0000x reference)
//
#include <hip/hip_runtime.h>

// SOM forward: x[128,256] f32, weights[64,64,256] f32
// out (f32, concatenated): bmus[128,2] (256 elems) then diffs[128,64,64,256]
#define BATCH 128
#define SOM_ROWS 64
#define SOM_COLS 64
#define M (SOM_ROWS * SOM_COLS)  // 4096
#define D 256
#define DV (D / 4)               // 64 float4 per row == one wave's lanes

typedef float f32x4 __attribute__((ext_vector_type(4)));

// ---------------------------------------------------------------------------
// Kernel A: pure streaming diffs write. No reduction in the hot loop.
// One wave per m (w-row held in registers); b varies per iteration, unrolled
// x4 so four independent load->sub->store chains are in flight.
// Non-temporal stores: the 537 MB stream must not thrash the L2 copies of
// x (128 KB) and w (4 MB) that the loads rely on.
// ---------------------------------------------------------------------------
__global__ void __launch_bounds__(256) som_diffs(const float* __restrict__ x,
                                                 const float* __restrict__ w,
                                                 float* __restrict__ diffs) {
  const int lane = threadIdx.x & 63;
  const int wib = threadIdx.x >> 6;
  const int gwave = blockIdx.x * (blockDim.x >> 6) + wib;  // 0..8191
  const int m = gwave & (M - 1);   // w-row for this wave (fixed)
  const int b0 = gwave >> 12;      // 0 or 1: even or odd batch rows

  const f32x4* __restrict__ x4 = (const f32x4*)x;
  const f32x4* __restrict__ w4 = (const f32x4*)w;
  f32x4* __restrict__ o4 = (f32x4*)diffs;

  const f32x4 wv = w4[m * DV + lane];  // loop-invariant w fragment

  // b0=0 covers even b (0,2,..,126); b0=1 covers odd b (1,3,..,127).
  for (int b = b0; b < BATCH; b += 8) {
    f32x4 x0 = x4[(b + 0) * DV + lane];
    f32x4 x1 = x4[(b + 2) * DV + lane];
    f32x4 x2 = x4[(b + 4) * DV + lane];
    f32x4 x3 = x4[(b + 6) * DV + lane];
    f32x4 d0 = x0 - wv;
    f32x4 d1 = x1 - wv;
    f32x4 d2 = x2 - wv;
    f32x4 d3 = x3 - wv;
    __builtin_nontemporal_store(d0, &o4[((long)(b + 0) * M + m) * DV + lane]);
    __builtin_nontemporal_store(d1, &o4[((long)(b + 2) * M + m) * DV + lane]);
    __builtin_nontemporal_store(d2, &o4[((long)(b + 4) * M + m) * DV + lane]);
    __builtin_nontemporal_store(d3, &o4[((long)(b + 6) * M + m) * DV + lane]);
  }
}

// ---------------------------------------------------------------------------
// Kernel B: distances + argmin fused, computed directly from x,w (L2-resident,
// 4 MB). One block per batch element, 8 waves. Each wave step covers 4 w-rows
// with 16 lanes per row (g = lane>>4 row, c = lane&15 col), so every vector
// load instruction touches 16 fully-used cachelines (4 rows x 256 B). Reduce
// across the 16 c-lanes with 4 shfl_xor; first-index tie-break like argmin.
// ---------------------------------------------------------------------------
__global__ void __launch_bounds__(512) som_dist_argmin(
    const float* __restrict__ x, const float* __restrict__ w,
    float* __restrict__ out) {
  __shared__ f32x4 xs[DV];     // x[b], 1 KB
  __shared__ float sval[512];
  __shared__ int sidx[512];
  const int b = blockIdx.x;
  const int t = threadIdx.x;
  const int lane = t & 63;
  const int wid = t >> 6;      // 0..7
  const int g = lane >> 4;     // 0..3  : row within the 4-row group
  const int c = lane & 15;     // 0..15 : float4 index within a 256 B chunk

  const f32x4* __restrict__ x4 = (const f32x4*)x;
  const f32x4* __restrict__ w4 = (const f32x4*)w;

  if (t < DV) xs[t] = x4[b * DV + t];
  __syncthreads();

  float best = 3.4e38f;
  int bidx = 0x7fffffff;

  // wave wid owns m in [wid*512, wid*512+512), 4 rows per step; m increases
  // monotonically per lane so strict < keeps the earliest index.
  for (int step = 0; step < 128; ++step) {
    const int m = (wid << 9) + (step << 2) + g;
    float s = 0.f;
#pragma unroll
    for (int j = 0; j < 4; ++j) {
      const f32x4 wv = w4[(long)m * DV + (j << 4) + c];
      const f32x4 xv = xs[(j << 4) + c];
      const f32x4 df = xv - wv;
      s += df.x * df.x + df.y * df.y + df.z * df.z + df.w * df.w;
    }
    s += __shfl_xor(s, 1, 64);
    s += __shfl_xor(s, 2, 64);
    s += __shfl_xor(s, 4, 64);
    s += __shfl_xor(s, 8, 64);
    if (s < best) {  // strict <: earliest m within this lane's stream
      best = s;
      bidx = m;
    }
  }

  sval[t] = best;
  sidx[t] = bidx;
  __syncthreads();
  for (int sr = 256; sr; sr >>= 1) {
    if (t < sr) {
      const float v2 = sval[t + sr];
      const int i2 = sidx[t + sr];
      if (v2 < sval[t] || (v2 == sval[t] && i2 < sidx[t])) {
        sval[t] = v2;
        sidx[t] = i2;
      }
    }
    __syncthreads();
  }
  if (t == 0) {
    out[2 * b] = (float)(sidx[0] >> 6);       // row = m / 64
    out[2 * b + 1] = (float)(sidx[0] & 63);   // col = m % 64
  }
}

extern "C" void kernel_launch(void* const* d_in, const int* in_sizes, int n_in,
                              void* d_out, int out_size, void* d_ws,
                              size_t ws_size, hipStream_t stream) {
  const float* x = (const float*)d_in[0];  // [128,256]
  const float* w = (const float*)d_in[1];  // [64,64,256]
  float* out = (float*)d_out;
  float* bmus = out;                       // first 256 floats
  float* diffs = out + 2 * BATCH;          // then 128*64*64*256

  // Small kernel first (also warms w into L2), then the big stream.
  som_dist_argmin<<<BATCH, 512, 0, stream>>>(x, w, bmus);
  som_diffs<<<2048, 256, 0, stream>>>(x, w, diffs);
}

// Round 3
// 569.551 us; speedup vs baseline: 1.0706x; 1.0706x over previous
//
#include <hip/hip_runtime.h>

// SOM forward: x[128,256] f32, weights[64,64,256] f32
// out (f32, concatenated): bmus[128,2] (256 elems) then diffs[128,64,64,256]
#define BATCH 128
#define SOM_ROWS 64
#define SOM_COLS 64
#define M (SOM_ROWS * SOM_COLS)  // 4096
#define D 256
#define DV (D / 4)               // 64 float4 per row == one wave's lanes

typedef float f32x4 __attribute__((ext_vector_type(4)));

// ---------------------------------------------------------------------------
// Kernel A: streaming diffs write with FILL-LIKE address walk.
// Wave g owns a CONTIGUOUS 64 KB span of diffs: b = g>>6 (fixed -> x[b] row
// held in registers), m walks 64 consecutive w-rows. Store address is
// g*64KB + mi*1KB + lane*16B — purely sequential per wave, adjacent across
// waves, mimicking the 6.3 TB/s fill kernel. w rows stream from L2 (4 MB,
// resident; warmed by kernel B). Non-temporal stores keep the 537 MB stream
// from evicting x/w.
// ---------------------------------------------------------------------------
__global__ void __launch_bounds__(256) som_diffs(const float* __restrict__ x,
                                                 const float* __restrict__ w,
                                                 float* __restrict__ diffs) {
  const int lane = threadIdx.x & 63;
  const int wib = threadIdx.x >> 6;
  const int g = blockIdx.x * (blockDim.x >> 6) + wib;  // 0..8191
  const int b = g >> 6;            // fixed batch row for this wave
  const int mbase = (g & 63) << 6; // 64 consecutive m's

  const f32x4* __restrict__ x4 = (const f32x4*)x;
  const f32x4* __restrict__ w4 = (const f32x4*)w;
  f32x4* __restrict__ o4 = (f32x4*)diffs;

  const f32x4 xv = x4[b * DV + lane];  // loop-invariant x fragment
  // Base of this wave's contiguous span (in float4 units): g*4096 + lane.
  f32x4* __restrict__ op = o4 + ((long)g << 12) + lane;
  const f32x4* __restrict__ wp = w4 + ((long)mbase << 6) + lane;

  for (int mi = 0; mi < 64; mi += 4) {
    const f32x4 w0 = wp[(mi + 0) << 6];
    const f32x4 w1 = wp[(mi + 1) << 6];
    const f32x4 w2 = wp[(mi + 2) << 6];
    const f32x4 w3 = wp[(mi + 3) << 6];
    const f32x4 d0 = xv - w0;
    const f32x4 d1 = xv - w1;
    const f32x4 d2 = xv - w2;
    const f32x4 d3 = xv - w3;
    __builtin_nontemporal_store(d0, &op[(mi + 0) << 6]);
    __builtin_nontemporal_store(d1, &op[(mi + 1) << 6]);
    __builtin_nontemporal_store(d2, &op[(mi + 2) << 6]);
    __builtin_nontemporal_store(d3, &op[(mi + 3) << 6]);
  }
}

// ---------------------------------------------------------------------------
// Kernel B: distances + argmin fused, from x,w directly. 128 blocks x 1024
// threads (16 waves: 4/SIMD, 2x round-2's latency hiding). Wave wid owns
// m in [wid*256, wid*256+256), 4 rows per step (g = lane>>4 row, c = lane&15
// col) -> every load touches 16 fully-used cachelines. Also warms w into L2
// on every XCD before kernel A streams it.
// ---------------------------------------------------------------------------
__global__ void __launch_bounds__(1024) som_dist_argmin(
    const float* __restrict__ x, const float* __restrict__ w,
    float* __restrict__ out) {
  __shared__ f32x4 xs[DV];      // x[b], 1 KB
  __shared__ float sval[1024];
  __shared__ int sidx[1024];
  const int b = blockIdx.x;
  const int t = threadIdx.x;
  const int lane = t & 63;
  const int wid = t >> 6;       // 0..15
  const int g = lane >> 4;      // 0..3  : row within the 4-row group
  const int c = lane & 15;      // 0..15 : float4 index within a 256 B chunk

  const f32x4* __restrict__ x4 = (const f32x4*)x;
  const f32x4* __restrict__ w4 = (const f32x4*)w;

  if (t < DV) xs[t] = x4[b * DV + t];
  __syncthreads();

  float best = 3.4e38f;
  int bidx = 0x7fffffff;

  // 64 steps x 4 rows = 256 m's per wave; m increases monotonically per lane
  // so strict < keeps the earliest index.
  for (int step = 0; step < 64; ++step) {
    const int m = (wid << 8) + (step << 2) + g;
    float s = 0.f;
#pragma unroll
    for (int j = 0; j < 4; ++j) {
      const f32x4 wv = w4[(long)m * DV + (j << 4) + c];
      const f32x4 xv = xs[(j << 4) + c];
      const f32x4 df = xv - wv;
      s += df.x * df.x + df.y * df.y + df.z * df.z + df.w * df.w;
    }
    s += __shfl_xor(s, 1, 64);
    s += __shfl_xor(s, 2, 64);
    s += __shfl_xor(s, 4, 64);
    s += __shfl_xor(s, 8, 64);
    if (s < best) {
      best = s;
      bidx = m;
    }
  }

  sval[t] = best;
  sidx[t] = bidx;
  __syncthreads();
  for (int sr = 512; sr; sr >>= 1) {
    if (t < sr) {
      const float v2 = sval[t + sr];
      const int i2 = sidx[t + sr];
      if (v2 < sval[t] || (v2 == sval[t] && i2 < sidx[t])) {
        sval[t] = v2;
        sidx[t] = i2;
      }
    }
    __syncthreads();
  }
  if (t == 0) {
    out[2 * b] = (float)(sidx[0] >> 6);      // row = m / 64
    out[2 * b + 1] = (float)(sidx[0] & 63);  // col = m % 64
  }
}

extern "C" void kernel_launch(void* const* d_in, const int* in_sizes, int n_in,
                              void* d_out, int out_size, void* d_ws,
                              size_t ws_size, hipStream_t stream) {
  const float* x = (const float*)d_in[0];  // [128,256]
  const float* w = (const float*)d_in[1];  // [64,64,256]
  float* out = (float*)d_out;
  float* bmus = out;                       // first 256 floats
  float* diffs = out + 2 * BATCH;          // then 128*64*64*256

  // Argmin first (also warms w into every XCD's L2), then the big stream.
  som_dist_argmin<<<BATCH, 1024, 0, stream>>>(x, w, bmus);
  som_diffs<<<2048, 256, 0, stream>>>(x, w, diffs);
}